// Round 1
// baseline (435.833 us; speedup 1.0000x reference)
//
#include <hip/hip_runtime.h>
#include <hip/hip_bf16.h>
#include <stdint.h>

#define HIDDEN 1024
#define TOKENS 32768
#define NE 8

typedef unsigned short u16;
typedef short bf16x8 __attribute__((ext_vector_type(8)));
typedef float f32x4 __attribute__((ext_vector_type(4)));

// ---------------- K0: expert_weight [h][d] fp32 -> Bt [d][h] bf16 (transpose+convert)
__global__ __launch_bounds__(256) void k0_transpose(const float* __restrict__ B,
                                                    u16* __restrict__ Bt) {
  __shared__ float tile[64][65];
  const int d0 = blockIdx.x * 64;
  const int h0 = blockIdx.y * 64;
  const int t = threadIdx.x;
#pragma unroll
  for (int p = 0; p < 16; ++p) {
    int idx = p * 256 + t;
    int r = idx >> 6, c = idx & 63;
    tile[r][c] = B[(size_t)(h0 + r) * HIDDEN + d0 + c];
  }
  __syncthreads();
#pragma unroll
  for (int p = 0; p < 16; ++p) {
    int idx = p * 256 + t;
    int r = idx >> 6, c = idx & 63;  // write Bt[d0+r][h0+c] = B[h0+c][d0+r]
    __hip_bfloat16 v = __float2bfloat16(tile[c][r]);
    Bt[(size_t)(d0 + r) * HIDDEN + h0 + c] = *(u16*)&v;
  }
}

// ---------------- K1: fp32 gating -> s[tok] = sum of top-2 of 8 logits
__global__ __launch_bounds__(256) void k1_gate(const float* __restrict__ H,
                                               const float* __restrict__ G,
                                               float* __restrict__ s) {
  __shared__ float g[NE * HIDDEN];  // 32 KiB
  const int t = threadIdx.x;
  for (int i = t; i < NE * HIDDEN; i += 256) g[i] = G[i];
  __syncthreads();
  const int lane = t & 63;
  const int gw = blockIdx.x * 4 + (t >> 6);
  const int nw = gridDim.x * 4;
  const float4* g4 = (const float4*)g;
  for (int tok = gw; tok < TOKENS; tok += nw) {
    const float4* h4 = (const float4*)(H + (size_t)tok * HIDDEN);
    float acc[NE];
#pragma unroll
    for (int e = 0; e < NE; ++e) acc[e] = 0.f;
#pragma unroll
    for (int p = 0; p < 4; ++p) {
      float4 v = h4[p * 64 + lane];
#pragma unroll
      for (int e = 0; e < NE; ++e) {
        float4 w = g4[e * 256 + p * 64 + lane];
        acc[e] += v.x * w.x + v.y * w.y + v.z * w.z + v.w * w.w;
      }
    }
#pragma unroll
    for (int e = 0; e < NE; ++e) {
#pragma unroll
      for (int off = 32; off > 0; off >>= 1) acc[e] += __shfl_xor(acc[e], off, 64);
    }
    if (lane == 0) {
      float m1 = -3.0e38f, m2 = -3.0e38f;
#pragma unroll
      for (int e = 0; e < NE; ++e) {
        float v = acc[e];
        if (v > m1) { m2 = m1; m1 = v; }
        else if (v > m2) { m2 = v; }
      }
      s[tok] = m1 + m2;
    }
  }
}

// ---------------- K2: C[m][n] = sum_k A[m][k] * Bt[n][k], bf16 MFMA 16x16x32
#define BM 128
#define BN 128
#define BK 32
#define LDST 40  // LDS row stride in elements: 80 B, 16B-aligned, <=2-way bank aliasing

__global__ __launch_bounds__(256, 2) void k2_gemm(const float* __restrict__ A,
                                                  const u16* __restrict__ Bt,
                                                  u16* __restrict__ C) {
  __shared__ u16 As[BM * LDST];
  __shared__ u16 Bs[BN * LDST];
  const int t = threadIdx.x;
  const int lane = t & 63;
  const int wave = t >> 6;
  const int m0 = blockIdx.y * BM;
  const int n0 = blockIdx.x * BN;
  const int wm = (wave >> 1) * 64;
  const int wn = (wave & 1) * 64;
  const int lm = lane & 15;
  const int lq = lane >> 4;

  const int ra = t >> 1;         // tile row 0..127 (both A and B staging)
  const int ha = (t & 1) * 16;   // element offset within 32-wide k-slice
  const float* Ap = A + (size_t)(m0 + ra) * HIDDEN + ha;
  const u16* Bp = Bt + (size_t)(n0 + ra) * HIDDEN + ha;

  f32x4 acc[4][4];
#pragma unroll
  for (int i = 0; i < 4; ++i)
#pragma unroll
    for (int j = 0; j < 4; ++j) acc[i][j] = (f32x4){0.f, 0.f, 0.f, 0.f};

  for (int kk = 0; kk < HIDDEN; kk += BK) {
    float4 a0 = *(const float4*)(Ap + kk);
    float4 a1 = *(const float4*)(Ap + kk + 4);
    float4 a2 = *(const float4*)(Ap + kk + 8);
    float4 a3 = *(const float4*)(Ap + kk + 12);
    uint4 b0 = *(const uint4*)(Bp + kk);
    uint4 b1 = *(const uint4*)(Bp + kk + 8);
    __syncthreads();  // previous iter's frag reads complete before overwrite
    union U { uint4 u; __hip_bfloat162 h[4]; } p0, p1;
    p0.h[0] = __float22bfloat162_rn(make_float2(a0.x, a0.y));
    p0.h[1] = __float22bfloat162_rn(make_float2(a0.z, a0.w));
    p0.h[2] = __float22bfloat162_rn(make_float2(a1.x, a1.y));
    p0.h[3] = __float22bfloat162_rn(make_float2(a1.z, a1.w));
    p1.h[0] = __float22bfloat162_rn(make_float2(a2.x, a2.y));
    p1.h[1] = __float22bfloat162_rn(make_float2(a2.z, a2.w));
    p1.h[2] = __float22bfloat162_rn(make_float2(a3.x, a3.y));
    p1.h[3] = __float22bfloat162_rn(make_float2(a3.z, a3.w));
    *(uint4*)&As[ra * LDST + ha] = p0.u;
    *(uint4*)&As[ra * LDST + ha + 8] = p1.u;
    *(uint4*)&Bs[ra * LDST + ha] = b0;
    *(uint4*)&Bs[ra * LDST + ha + 8] = b1;
    __syncthreads();
    bf16x8 af[4], bfr[4];
#pragma unroll
    for (int i = 0; i < 4; ++i)
      af[i] = *(const bf16x8*)&As[(wm + i * 16 + lm) * LDST + lq * 8];
#pragma unroll
    for (int j = 0; j < 4; ++j)
      bfr[j] = *(const bf16x8*)&Bs[(wn + j * 16 + lm) * LDST + lq * 8];
#pragma unroll
    for (int i = 0; i < 4; ++i)
#pragma unroll
      for (int j = 0; j < 4; ++j)
        acc[i][j] = __builtin_amdgcn_mfma_f32_16x16x32_bf16(af[i], bfr[j], acc[i][j], 0, 0, 0);
  }

  // epilogue: write C as bf16. C/D layout: col=lane&15, row=(lane>>4)*4+reg.
#pragma unroll
  for (int i = 0; i < 4; ++i) {
#pragma unroll
    for (int r = 0; r < 4; ++r) {
      int row = m0 + wm + i * 16 + lq * 4 + r;
      size_t base = (size_t)row * HIDDEN + n0 + wn + lm;
#pragma unroll
      for (int j = 0; j < 4; ++j) {
        __hip_bfloat16 v = __float2bfloat16(acc[i][j][r]);
        C[base + j * 16] = *(u16*)&v;
      }
    }
  }
}

// ---------------- K3: LayerNorm( s[tok] * C[tok][:] ) -> out fp32
__global__ __launch_bounds__(256) void k3_ln(const u16* __restrict__ C,
                                             const float* __restrict__ s,
                                             const float* __restrict__ gamma,
                                             const float* __restrict__ beta,
                                             float* __restrict__ out) {
  const int t = threadIdx.x;
  const int lane = t & 63;
  const int tok = blockIdx.x * 4 + (t >> 6);
  const float sc = s[tok];
  const uint4* row = (const uint4*)(C + (size_t)tok * HIDDEN);
  float x[16];
  float sum = 0.f, sq = 0.f;
#pragma unroll
  for (int p = 0; p < 2; ++p) {
    union { uint4 u; u16 us[8]; } v;
    v.u = row[p * 64 + lane];
#pragma unroll
    for (int i = 0; i < 8; ++i) {
      float f = __uint_as_float(((unsigned)v.us[i]) << 16) * sc;
      x[p * 8 + i] = f;
      sum += f;
      sq += f * f;
    }
  }
#pragma unroll
  for (int off = 32; off > 0; off >>= 1) {
    sum += __shfl_xor(sum, off, 64);
    sq += __shfl_xor(sq, off, 64);
  }
  const float mean = sum * (1.f / HIDDEN);
  const float var = sq * (1.f / HIDDEN) - mean * mean;
  const float rstd = rsqrtf(var + 1e-5f);
  const float4* g4 = (const float4*)gamma;
  const float4* b4 = (const float4*)beta;
#pragma unroll
  for (int p = 0; p < 2; ++p) {
    int e4 = (p * 64 + lane) * 2;  // float4 index; element base = e4*4
    float4 gm0 = g4[e4], gm1 = g4[e4 + 1];
    float4 bt0 = b4[e4], bt1 = b4[e4 + 1];
    float4 o0, o1;
    o0.x = (x[p * 8 + 0] - mean) * rstd * gm0.x + bt0.x;
    o0.y = (x[p * 8 + 1] - mean) * rstd * gm0.y + bt0.y;
    o0.z = (x[p * 8 + 2] - mean) * rstd * gm0.z + bt0.z;
    o0.w = (x[p * 8 + 3] - mean) * rstd * gm0.w + bt0.w;
    o1.x = (x[p * 8 + 4] - mean) * rstd * gm1.x + bt1.x;
    o1.y = (x[p * 8 + 5] - mean) * rstd * gm1.y + bt1.y;
    o1.z = (x[p * 8 + 6] - mean) * rstd * gm1.z + bt1.z;
    o1.w = (x[p * 8 + 7] - mean) * rstd * gm1.w + bt1.w;
    float* op = out + (size_t)tok * HIDDEN + e4 * 4;
    *(float4*)op = o0;
    *(float4*)(op + 4) = o1;
  }
}

extern "C" void kernel_launch(void* const* d_in, const int* in_sizes, int n_in,
                              void* d_out, int out_size, void* d_ws, size_t ws_size,
                              hipStream_t stream) {
  (void)in_sizes; (void)n_in; (void)out_size; (void)ws_size;
  const float* H = (const float*)d_in[0];      // [4,8192,1024] fp32
  const float* G = (const float*)d_in[1];      // [8,1024] fp32
  const float* W = (const float*)d_in[2];      // [1024,1024] fp32
  const float* gamma = (const float*)d_in[3];  // [1024]
  const float* beta = (const float*)d_in[4];   // [1024]
  float* out = (float*)d_out;

  char* ws = (char*)d_ws;
  u16* Bt = (u16*)ws;                                        // 2 MiB
  float* s = (float*)(ws + (size_t)(2u << 20));              // 128 KiB
  u16* C = (u16*)(ws + (size_t)(2u << 20) + (256u << 10));   // 64 MiB

  k0_transpose<<<dim3(16, 16), 256, 0, stream>>>(W, Bt);
  k1_gate<<<1024, 256, 0, stream>>>(H, G, s);
  // grid.x = N-tiles (8) innermost: consecutive blocks share the A row-panel in L2
  k2_gemm<<<dim3(HIDDEN / BN, TOKENS / BM), 256, 0, stream>>>(H, Bt, C);
  k3_ln<<<TOKENS / 4, 256, 0, stream>>>(C, s, gamma, beta, out);
}

// Round 2
// 345.698 us; speedup vs baseline: 1.2607x; 1.2607x over previous
//
#include <hip/hip_runtime.h>
#include <hip/hip_bf16.h>
#include <stdint.h>

#define HIDDEN 1024
#define TOKENS 32768
#define NE 8

typedef unsigned short u16;
typedef short bf16x8 __attribute__((ext_vector_type(8)));
typedef float f32x4 __attribute__((ext_vector_type(4)));

__device__ __forceinline__ void gload_lds16(const void* g, void* l) {
  __builtin_amdgcn_global_load_lds(
      (const __attribute__((address_space(1))) void*)g,
      (__attribute__((address_space(3))) void*)l, 16, 0, 0);
}

// ---------------- K0: expert_weight [h][d] fp32 -> Bt [d][h] bf16 (transpose+convert)
__global__ __launch_bounds__(256) void k0_transpose(const float* __restrict__ B,
                                                    u16* __restrict__ Bt) {
  __shared__ float tile[64][65];
  const int d0 = blockIdx.x * 64;
  const int h0 = blockIdx.y * 64;
  const int t = threadIdx.x;
#pragma unroll
  for (int p = 0; p < 16; ++p) {
    int idx = p * 256 + t;
    int r = idx >> 6, c = idx & 63;
    tile[r][c] = B[(size_t)(h0 + r) * HIDDEN + d0 + c];
  }
  __syncthreads();
#pragma unroll
  for (int p = 0; p < 16; ++p) {
    int idx = p * 256 + t;
    int r = idx >> 6, c = idx & 63;
    __hip_bfloat16 v = __float2bfloat16(tile[c][r]);
    Bt[(size_t)(d0 + r) * HIDDEN + h0 + c] = *(u16*)&v;
  }
}

// ---------------- K1: fp32 gating -> s[tok]; also emit A as bf16 (fused convert)
// Gate weights live in registers: w[e][p] = G[e][p*256 + lane*4 .. +3]
__global__ __launch_bounds__(256) void k1_gate(const float* __restrict__ H,
                                               const float* __restrict__ G,
                                               float* __restrict__ s,
                                               u16* __restrict__ Abf) {
  const int t = threadIdx.x;
  const int lane = t & 63;
  const int wave = t >> 6;
  float4 w[NE][4];
#pragma unroll
  for (int e = 0; e < NE; ++e)
#pragma unroll
    for (int p = 0; p < 4; ++p)
      w[e][p] = *(const float4*)(G + e * HIDDEN + p * 256 + lane * 4);

  const int gw = blockIdx.x * 4 + wave;   // 2048 wave-slots (512 blocks)
  const int nw = gridDim.x * 4;
  for (int tok = gw; tok < TOKENS; tok += nw) {
    const float* hrow = H + (size_t)tok * HIDDEN;
    float4 h[4];
#pragma unroll
    for (int p = 0; p < 4; ++p) h[p] = *(const float4*)(hrow + p * 256 + lane * 4);

    // fused A bf16 write (coalesced 8B/lane)
#pragma unroll
    for (int p = 0; p < 4; ++p) {
      __hip_bfloat162 lo = __float22bfloat162_rn(make_float2(h[p].x, h[p].y));
      __hip_bfloat162 hi = __float22bfloat162_rn(make_float2(h[p].z, h[p].w));
      uint2 pk;
      pk.x = *(unsigned*)&lo;
      pk.y = *(unsigned*)&hi;
      *(uint2*)(Abf + (size_t)tok * HIDDEN + p * 256 + lane * 4) = pk;
    }

    float acc[NE];
#pragma unroll
    for (int e = 0; e < NE; ++e) acc[e] = 0.f;
#pragma unroll
    for (int p = 0; p < 4; ++p)
#pragma unroll
      for (int e = 0; e < NE; ++e)
        acc[e] += h[p].x * w[e][p].x + h[p].y * w[e][p].y +
                  h[p].z * w[e][p].z + h[p].w * w[e][p].w;
#pragma unroll
    for (int e = 0; e < NE; ++e) {
#pragma unroll
      for (int off = 32; off > 0; off >>= 1) acc[e] += __shfl_xor(acc[e], off, 64);
    }
    if (lane == 0) {
      float m1 = -3.0e38f, m2 = -3.0e38f;
#pragma unroll
      for (int e = 0; e < NE; ++e) {
        float v = acc[e];
        if (v > m1) { m2 = m1; m1 = v; }
        else if (v > m2) { m2 = v; }
      }
      s[tok] = m1 + m2;
    }
  }
}

// ---------------- K2: C[m][n] = sum_k A[m][k]*Bt[n][k], bf16 MFMA, m97 structure
#define BM 128
#define BN 128
#define BK 32

__global__ __launch_bounds__(256, 4) void k2_gemm(const u16* __restrict__ A,
                                                  const u16* __restrict__ Bt,
                                                  u16* __restrict__ C) {
  __shared__ u16 As[BM * BK];  // 8 KiB, unpadded (global_load_lds layout)
  __shared__ u16 Bs[BN * BK];  // 8 KiB
  const int t = threadIdx.x;
  const int lane = t & 63;
  const int wave = t >> 6;

  // XCD-aware mapping: xcd = b%8 owns M-panels [xcd*32, xcd*32+32); 8 N-tiles
  // of one panel are consecutive within the XCD for L2 A-panel reuse.
  const int b = blockIdx.x;
  const int m0 = ((b & 7) * 32 + ((b >> 3) >> 3)) * BM;
  const int n0 = (((b >> 3) & 7)) * BN;

  const int wm = (wave >> 1) * 64;
  const int wn = (wave & 1) * 64;
  const int lm = lane & 15;
  const int lq = lane >> 4;

  // staging lane-slots: L0 = t (rows 0..63), L1 = 256+t (rows 64..127)
  // LDS slot (r, qs) holds global k-chunk q = qs ^ sw(r), sw(r)=(r^(r>>2))&3
  const int r0 = t >> 2;
  const int q0 = (t & 3) ^ ((r0 ^ (r0 >> 2)) & 3);
  const int r1 = (256 + t) >> 2;
  const int q1 = (t & 3) ^ ((r1 ^ (r1 >> 2)) & 3);
  const u16* A0 = A + (size_t)(m0 + r0) * HIDDEN + q0 * 8;
  const u16* A1 = A + (size_t)(m0 + r1) * HIDDEN + q1 * 8;
  const u16* B0 = Bt + (size_t)(n0 + r0) * HIDDEN + q0 * 8;
  const u16* B1 = Bt + (size_t)(n0 + r1) * HIDDEN + q1 * 8;
  u16* lA0 = &As[t * 8];
  u16* lA1 = &As[(256 + t) * 8];
  u16* lB0 = &Bs[t * 8];
  u16* lB1 = &Bs[(256 + t) * 8];

  // frag-read slot: row&15 == lm for all i, so sw(row) depends only on lm
  const int slot = lq ^ ((lm ^ (lm >> 2)) & 3);

  f32x4 acc[4][4];
#pragma unroll
  for (int i = 0; i < 4; ++i)
#pragma unroll
    for (int j = 0; j < 4; ++j) acc[i][j] = (f32x4){0.f, 0.f, 0.f, 0.f};

  for (int kk = 0; kk < HIDDEN; kk += BK) {
    __syncthreads();  // prev iter's frag reads complete before LDS overwrite
    gload_lds16(A0 + kk, lA0);
    gload_lds16(A1 + kk, lA1);
    gload_lds16(B0 + kk, lB0);
    gload_lds16(B1 + kk, lB1);
    __syncthreads();  // compiler drains vmcnt(0) before barrier => tiles visible

    bf16x8 af[4], bfr[4];
#pragma unroll
    for (int i = 0; i < 4; ++i)
      af[i] = *(const bf16x8*)&As[(wm + i * 16 + lm) * BK + slot * 8];
#pragma unroll
    for (int j = 0; j < 4; ++j)
      bfr[j] = *(const bf16x8*)&Bs[(wn + j * 16 + lm) * BK + slot * 8];
#pragma unroll
    for (int i = 0; i < 4; ++i)
#pragma unroll
      for (int j = 0; j < 4; ++j)
        acc[i][j] = __builtin_amdgcn_mfma_f32_16x16x32_bf16(af[i], bfr[j], acc[i][j], 0, 0, 0);
  }

  // epilogue: C/D layout col=lane&15, row=(lane>>4)*4+reg
#pragma unroll
  for (int i = 0; i < 4; ++i) {
#pragma unroll
    for (int r = 0; r < 4; ++r) {
      int row = m0 + wm + i * 16 + lq * 4 + r;
      size_t base = (size_t)row * HIDDEN + n0 + wn + lm;
#pragma unroll
      for (int j = 0; j < 4; ++j) {
        __hip_bfloat16 v = __float2bfloat16(acc[i][j][r]);
        C[base + j * 16] = *(u16*)&v;
      }
    }
  }
}

// ---------------- K3: LayerNorm( s[tok] * C[tok][:] ) -> out fp32
__global__ __launch_bounds__(256) void k3_ln(const u16* __restrict__ C,
                                             const float* __restrict__ s,
                                             const float* __restrict__ gamma,
                                             const float* __restrict__ beta,
                                             float* __restrict__ out) {
  const int t = threadIdx.x;
  const int lane = t & 63;
  const int tok = blockIdx.x * 4 + (t >> 6);
  const float sc = s[tok];
  const uint4* row = (const uint4*)(C + (size_t)tok * HIDDEN);
  float x[16];
  float sum = 0.f, sq = 0.f;
#pragma unroll
  for (int p = 0; p < 2; ++p) {
    union { uint4 u; u16 us[8]; } v;
    v.u = row[p * 64 + lane];
#pragma unroll
    for (int i = 0; i < 8; ++i) {
      float f = __uint_as_float(((unsigned)v.us[i]) << 16) * sc;
      x[p * 8 + i] = f;
      sum += f;
      sq += f * f;
    }
  }
#pragma unroll
  for (int off = 32; off > 0; off >>= 1) {
    sum += __shfl_xor(sum, off, 64);
    sq += __shfl_xor(sq, off, 64);
  }
  const float mean = sum * (1.f / HIDDEN);
  const float var = sq * (1.f / HIDDEN) - mean * mean;
  const float rstd = rsqrtf(var + 1e-5f);
  const float4* g4 = (const float4*)gamma;
  const float4* b4 = (const float4*)beta;
#pragma unroll
  for (int p = 0; p < 2; ++p) {
    int e4 = (p * 64 + lane) * 2;
    float4 gm0 = g4[e4], gm1 = g4[e4 + 1];
    float4 bt0 = b4[e4], bt1 = b4[e4 + 1];
    float4 o0, o1;
    o0.x = (x[p * 8 + 0] - mean) * rstd * gm0.x + bt0.x;
    o0.y = (x[p * 8 + 1] - mean) * rstd * gm0.y + bt0.y;
    o0.z = (x[p * 8 + 2] - mean) * rstd * gm0.z + bt0.z;
    o0.w = (x[p * 8 + 3] - mean) * rstd * gm0.w + bt0.w;
    o1.x = (x[p * 8 + 4] - mean) * rstd * gm1.x + bt1.x;
    o1.y = (x[p * 8 + 5] - mean) * rstd * gm1.y + bt1.y;
    o1.z = (x[p * 8 + 6] - mean) * rstd * gm1.z + bt1.z;
    o1.w = (x[p * 8 + 7] - mean) * rstd * gm1.w + bt1.w;
    float* op = out + (size_t)tok * HIDDEN + e4 * 4;
    *(float4*)op = o0;
    *(float4*)(op + 4) = o1;
  }
}

extern "C" void kernel_launch(void* const* d_in, const int* in_sizes, int n_in,
                              void* d_out, int out_size, void* d_ws, size_t ws_size,
                              hipStream_t stream) {
  (void)in_sizes; (void)n_in; (void)out_size; (void)ws_size;
  const float* H = (const float*)d_in[0];      // [4,8192,1024] fp32
  const float* G = (const float*)d_in[1];      // [8,1024] fp32
  const float* W = (const float*)d_in[2];      // [1024,1024] fp32
  const float* gamma = (const float*)d_in[3];  // [1024]
  const float* beta = (const float*)d_in[4];   // [1024]
  float* out = (float*)d_out;

  char* ws = (char*)d_ws;
  u16* Bt = (u16*)ws;                                        // 2 MiB
  float* s = (float*)(ws + (size_t)(2u << 20));              // 128 KiB
  u16* C = (u16*)(ws + (size_t)(2u << 20) + (256u << 10));   // 64 MiB

  // A-bf16 scratch lives in d_out's first 67 MB (out is 134 MB fp32);
  // k2 consumes it, k3 overwrites d_out with the final result afterwards.
  u16* Abf = (u16*)d_out;

  k0_transpose<<<dim3(16, 16), 256, 0, stream>>>(W, Bt);
  k1_gate<<<512, 256, 0, stream>>>(H, G, s, Abf);
  k2_gemm<<<2048, 256, 0, stream>>>(Abf, Bt, C);
  k3_ln<<<TOKENS / 4, 256, 0, stream>>>(C, s, gamma, beta, out);
}